// Round 14
// baseline (377.903 us; speedup 1.0000x reference)
//
#include <hip/hip_runtime.h>
#include <math.h>

#define BB 64
#define TT 256
#define VV 256
#define SLABS 321            // slab s = t + v/4 in [0,318]; +2 pad for clamped prefetch
#define SLAB_F (SLABS * 256) // elements per batch per plane = 82176
#define PLANE ((size_t)BB * SLAB_F)       // elements per plane
#define EPLANE ((size_t)BB * SLABS * 64)  // ints in exponent plane
#define NSLAB_W 319          // slabs 0..318 hold at least one valid (t,v)
#define NCNT 704             // persistent counts blocks

typedef __attribute__((ext_vector_type(4))) _Float16 half4;

__device__ __forceinline__ float dpp_shr1_f(float x) {
    return __int_as_float(__builtin_amdgcn_update_dpp(
        __float_as_int(x), __float_as_int(x), 0x138, 0xF, 0xF, false));
}
__device__ __forceinline__ int dpp_shr1_i(int x) {
    return __builtin_amdgcn_update_dpp(x, x, 0x138, 0xF, 0xF, false);
}

__device__ __forceinline__ float lae2(float x, float y) {
    float m = fmaxf(x, y);
    float d = x - y;
    return m + __logf(1.0f + __expf(-fabsf(d)));
}

// Kernel 1 (diag-major): one block per (b, slab). Thread j owns v=j, t=s-(j>>2).
// FP16 prob planes (storage only; math fp32). Invalid-t lanes write prob 0.
__global__ void __launch_bounds__(256) k_prep(const float4* __restrict__ lg,
                                              float4* __restrict__ sc,
                                              _Float16* __restrict__ Dd,
                                              _Float16* __restrict__ Di,
                                              _Float16* __restrict__ Du) {
    int blk = blockIdx.x;
    int b = blk / NSLAB_W;
    int s = blk - b * NSLAB_W;
    int v = threadIdx.x;
    int t = s - (v >> 2);
    bool valid = (t >= 0) && (t < TT);
    int tc = valid ? t : 0;
    size_t ci = ((size_t)b << 16) | ((size_t)tc << 8) | (size_t)v;
    float4 x = lg[ci];
    float m = fmaxf(fmaxf(x.x, x.y), fmaxf(x.z, x.w));
    float e0 = __expf(x.x - m), e1 = __expf(x.y - m);
    float e2 = __expf(x.z - m), e3 = __expf(x.w - m);
    float ssum = e0 + e1 + e2 + e3;
    float l = m + __logf(ssum);
    if (valid) sc[ci] = make_float4(x.x - l, x.y - l, x.z - l, x.w - l);
    float rcp = valid ? (1.0f / ssum) : 0.0f;
    size_t pb = (size_t)b * SLAB_F + ((size_t)s << 8) + v;
    Dd[pb] = (_Float16)(e0 * rcp);
    Di[pb] = (_Float16)(e1 * rcp);
    Du[pb] = (_Float16)(e2 * rcp);
}

// Merged kernel: blocks 0..31 = DP role (r13 2-wave serial DP, threads>=128
// exit); blocks 32.. = persistent counts blocks gated on per-batch progress
// (device-scope release fence + agent acquire — G16 producer/consumer).
// DP publishes progress every 32 steps; counts of slab s needs only A<=s.
__global__ void __launch_bounds__(256) k_dpcnt(const _Float16* __restrict__ Pd,
                                               const _Float16* __restrict__ Pi,
                                               const _Float16* __restrict__ Pu,
                                               float* __restrict__ A,
                                               int* __restrict__ Ei,
                                               float* __restrict__ scalar_out,
                                               int* __restrict__ progress,
                                               float4* __restrict__ out) {
    if (blockIdx.x < 32) {
        // ---------------- DP role ----------------
        if (threadIdx.x >= 128) return;
        const int b = (blockIdx.x << 1) | (threadIdx.x >> 6);
        const int lane = threadIdx.x & 63;
        const bool l0 = (lane == 0);
        const size_t base = (size_t)b * SLAB_F + (lane << 2);

        const half4* __restrict__ pd = (const half4*)(Pd + base);
        const half4* __restrict__ pi = (const half4*)(Pi + base);
        const half4* __restrict__ pu = (const half4*)(Pu + base);
        float4* __restrict__ pa = (float4*)(A + base);
        int* __restrict__ pe = Ei + (size_t)b * SLABS * 64 + lane;
        const int SS = 64;

        half4 d0,d1,d2,d3,d4,d5,d6,d7;
        half4 i0,i1,i2,i3,i4,i5,i6,i7;
        half4 u0,u1,u2,u3,u4,u5,u6,u7;
        d0 = pd[0*SS]; i0 = pi[0*SS]; u0 = pu[0*SS];
        d1 = pd[1*SS]; i1 = pi[1*SS]; u1 = pu[1*SS];
        d2 = pd[2*SS]; i2 = pi[2*SS]; u2 = pu[2*SS];
        d3 = pd[3*SS]; i3 = pi[3*SS]; u3 = pu[3*SS];
        d4 = pd[4*SS]; i4 = pi[4*SS]; u4 = pu[4*SS];
        d5 = pd[5*SS]; i5 = pi[5*SS]; u5 = pu[5*SS];
        d6 = pd[6*SS]; i6 = pi[6*SS]; u6 = pu[6*SS];
        d7 = pd[7*SS]; i7 = pi[7*SS]; u7 = pu[7*SS];

        float A0 = 0.0f, A1 = 0.0f, A2 = 0.0f, A3 = 0.0f;
        int   E  = 0;
        float LC = 0.0f, LP = 0.0f;
        int   EC = 0,    EP = 0;
        float sA3 = 0.0f;
        int   sEn = 0;
        int s = 0;

#define STEP(DD, II, UU, FIXUP, CLAMP, CAP)                                       \
    {                                                                             \
        const half4 dl = DD, in = II, su = UU;                                    \
        {                                                                         \
            int sp = s + 8;                                                       \
            if (CLAMP) sp = sp > SLABS - 1 ? SLABS - 1 : sp;                      \
            DD = pd[sp * SS]; II = pi[sp * SS]; UU = pu[sp * SS];                 \
        }                                                                         \
        int E_eff = E;                                                            \
        bool isT0 = false;                                                        \
        if (FIXUP) {                                                              \
            isT0 = (s == lane);                                                   \
            E_eff = isT0 ? (l0 ? 0 : EC) : E;                                     \
        }                                                                         \
        const float lc = l0 ? 0.0f : ldexpf(LC, EC - E_eff);                      \
        const float lp = l0 ? 0.0f : ldexpf(LP, EP - E_eff);                      \
        float X0 = (float)dl.x * A0 + (float)su.x * lp;                           \
        float X1 = (float)dl.y * A1 + (float)su.y * A0;                           \
        float X2 = (float)dl.z * A2 + (float)su.z * A1;                           \
        float X3 = (float)dl.w * A3 + (float)su.w * A2;                           \
        if (FIXUP && isT0) {                                                      \
            X0 = l0 ? 1.0f : 0.0f; X1 = 0.0f; X2 = 0.0f; X3 = 0.0f;               \
        }                                                                         \
        const float iy = (float)in.y, iz = (float)in.z, iw = (float)in.w;         \
        const float B0 = X0;                                                      \
        const float B1 = fmaf(B0, iy, X1);                                        \
        const float B2 = fmaf(B1, iz, X2);                                        \
        const float B3 = fmaf(B2, iw, X3);                                        \
        const float Q0 = (float)in.x;                                             \
        const float Q1 = Q0 * iy;                                                 \
        const float Q2 = Q1 * iz;                                                 \
        const float Q3 = Q2 * iw;                                                 \
        float nA0 = fmaf(lc, Q0, B0);                                             \
        float nA1 = fmaf(lc, Q1, B1);                                             \
        float nA2 = fmaf(lc, Q2, B2);                                             \
        float nA3 = fmaf(lc, Q3, B3);                                             \
        const int eb = (int)((__float_as_uint(nA3) >> 23) & 255u) - 126;          \
        const int En = E_eff + eb;                                                \
        nA3 = ldexpf(nA3, -eb);                                                   \
        nA0 = ldexpf(nA0, -eb);                                                   \
        nA1 = ldexpf(nA1, -eb);                                                   \
        nA2 = ldexpf(nA2, -eb);                                                   \
        LP = LC; EP = EC;                                                         \
        LC = dpp_shr1_f(nA3);                                                     \
        EC = dpp_shr1_i(En);                                                      \
        pa[s * SS] = make_float4(nA0, nA1, nA2, nA3);                             \
        pe[s * 64] = En;                                                          \
        if (CAP && s == TT + 62) { sA3 = nA3; sEn = En; }                         \
        A0 = nA0; A1 = nA1; A2 = nA2; A3 = nA3; E = En;                           \
        ++s;                                                                      \
    }
#define PUBLISH()                                                                 \
    {                                                                             \
        __threadfence();                                                          \
        if (l0) __hip_atomic_store(&progress[b], s - 1, __ATOMIC_RELEASE,         \
                                   __HIP_MEMORY_SCOPE_AGENT);                     \
    }

        // fill: s=0..63
#pragma unroll 1
        for (int it = 0; it < 8; ++it) {
            STEP(d0, i0, u0, 1, 0, 0);
            STEP(d1, i1, u1, 1, 0, 0);
            STEP(d2, i2, u2, 1, 0, 0);
            STEP(d3, i3, u3, 1, 0, 0);
            STEP(d4, i4, u4, 1, 0, 0);
            STEP(d5, i5, u5, 1, 0, 0);
            STEP(d6, i6, u6, 1, 0, 0);
            STEP(d7, i7, u7, 1, 0, 0);
            if ((it & 3) == 3) PUBLISH();
        }
        // steady: s=64..311
#pragma unroll 1
        for (int it = 0; it < 31; ++it) {
            STEP(d0, i0, u0, 0, 0, 0);
            STEP(d1, i1, u1, 0, 0, 0);
            STEP(d2, i2, u2, 0, 0, 0);
            STEP(d3, i3, u3, 0, 0, 0);
            STEP(d4, i4, u4, 0, 0, 0);
            STEP(d5, i5, u5, 0, 0, 0);
            STEP(d6, i6, u6, 0, 0, 0);
            STEP(d7, i7, u7, 0, 0, 0);
            if ((it & 3) == 3) PUBLISH();
        }
        // tail: s=312..319
        STEP(d0, i0, u0, 0, 1, 1);
        STEP(d1, i1, u1, 0, 1, 1);
        STEP(d2, i2, u2, 0, 1, 1);
        STEP(d3, i3, u3, 0, 1, 1);
        STEP(d4, i4, u4, 0, 1, 1);
        STEP(d5, i5, u5, 0, 1, 1);
        STEP(d6, i6, u6, 0, 1, 1);
        STEP(d7, i7, u7, 0, 1, 1);
        PUBLISH();   // publishes 319 (>= 318, covers all counts tasks)
#undef STEP
#undef PUBLISH

        if ((b == 0) && (lane == 63))
            scalar_out[0] = logf(sA3) + (float)sEn * 0.6931471805599453f;
    } else {
        // ---------------- counts role (persistent, gated) ----------------
        const int G = (int)gridDim.x - 32;
        const int v = threadIdx.x;
        const int g = v >> 2;
        __shared__ int s_go;
        for (int task = (int)blockIdx.x - 32; task < 64 * NSLAB_W; task += G) {
            int s = task >> 6;        // s-major: dp produces slabs in s order
            int b = task & 63;
            if (v == 0) {
                while (__hip_atomic_load(&progress[b], __ATOMIC_ACQUIRE,
                                         __HIP_MEMORY_SCOPE_AGENT) < s)
                    __builtin_amdgcn_s_sleep(2);
                s_go = 1;
            }
            __syncthreads();
            (void)s_go;

            int t = s - g;
            bool act = (t >= 0) && (t < TT);
            if (act) {
                size_t ab = (size_t)b * SLAB_F;
                size_t ebp = (size_t)b * SLABS * 64;
                int sm1 = s > 0 ? s - 1 : 0;
                int sm2 = s > 1 ? s - 2 : 0;
                int vm = v ? v - 1 : 0;
                int gm = g ? g - 1 : 0;
                bool v4 = (v & 3) == 0;

                float pD = (float)Pd[ab + ((size_t)s << 8) + v];
                float pI = (float)Pi[ab + ((size_t)s << 8) + v];
                float pU = (float)Pu[ab + ((size_t)s << 8) + v];
                float AA = A[ab + ((size_t)s   << 8) + v];
                float AU = A[ab + ((size_t)sm1 << 8) + v];
                int   EA = Ei[ebp + s   * 64 + g];
                int   EU = Ei[ebp + sm1 * 64 + g];
                float AL = v4 ? A[ab + ((size_t)sm1 << 8) + vm]
                              : A[ab + ((size_t)s   << 8) + vm];
                int   EL = v4 ? Ei[ebp + sm1 * 64 + gm] : EA;
                float AD = v4 ? A[ab + ((size_t)sm2 << 8) + vm]
                              : A[ab + ((size_t)sm1 << 8) + vm];
                int   ED = v4 ? Ei[ebp + sm2 * 64 + gm] : EU;

                bool tE = (t == 0) | (t == TT - 1);
                bool vE = (v == 0) | (v == VV - 1);
                float inv = 1.0f / AA;
                float w0 = ldexpf(pD * AU * inv, EU - EA);
                float w1 = ldexpf(pI * AL * inv, EL - EA);
                float w2 = ldexpf(pU * AD * inv, ED - EA);
                float4 o;
                o.x = tE ? 0.0f : (vE ? 1.0f : w0);
                o.y = vE ? 0.0f : (tE ? 1.0f : w1);
                o.z = (tE | vE) ? 0.0f : w2;
                o.w = 0.0f;
                out[((size_t)b << 16) | ((size_t)t << 8) | (size_t)v] = o;
            }
        }
    }
}

// Fallbacks for tiny ws.
__global__ void k_prep_legacy(const float4* __restrict__ lg, float4* __restrict__ sc, int n) {
    int i = blockIdx.x * blockDim.x + threadIdx.x;
    int st = gridDim.x * blockDim.x;
    for (; i < n; i += st) {
        float4 x = lg[i];
        float m = fmaxf(fmaxf(x.x, x.y), fmaxf(x.z, x.w));
        float s = __expf(x.x - m) + __expf(x.y - m) + __expf(x.z - m) + __expf(x.w - m);
        float l = m + __logf(s);
        sc[i] = make_float4(x.x - l, x.y - l, x.z - l, x.w - l);
    }
}
__global__ void __launch_bounds__(64) k_dp_legacy(const float4* __restrict__ scores,
                                                  float4* __restrict__ counts,
                                                  float* __restrict__ scalar_out) {
    const int b = blockIdx.x;
    const int lane = threadIdx.x;
    const int v0 = lane << 2;
    const float4* __restrict__ srow = scores + ((size_t)b * TT * VV + v0);
    float4* __restrict__ crow = counts + ((size_t)b * TT * VV + v0);
    float4 P0[4], P1[4], P2[4];
    {
        int r; const float4* p;
        r = 0 - lane; r = r < 0 ? 0 : r; p = srow + (size_t)r * VV;
        P0[0]=p[0]; P0[1]=p[1]; P0[2]=p[2]; P0[3]=p[3];
        r = 1 - lane; r = r < 0 ? 0 : r; p = srow + (size_t)r * VV;
        P1[0]=p[0]; P1[1]=p[1]; P1[2]=p[2]; P1[3]=p[3];
        r = 2 - lane; r = r < 0 ? 0 : r; p = srow + (size_t)r * VV;
        P2[0]=p[0]; P2[1]=p[1]; P2[2]=p[2]; P2[3]=p[3];
    }
    float aPrev[4] = { -INFINITY, -INFINITY, -INFINITY, -INFINITY };
    float leftPrev = -INFINITY, leftCur = -INFINITY;
    int s = 0;
#define STEPL(BUF)                                                                \
    {                                                                             \
        const int t = s - lane;                                                   \
        const bool active = (t >= 0) && (t < TT);                                 \
        float4 c0 = BUF[0], c1 = BUF[1], c2 = BUF[2], c3 = BUF[3];                \
        {                                                                         \
            int tp = t + 3; tp = tp < 0 ? 0 : tp; tp = tp > TT - 1 ? TT - 1 : tp; \
            const float4* lp = srow + (size_t)tp * VV;                            \
            BUF[0]=lp[0]; BUF[1]=lp[1]; BUF[2]=lp[2]; BUF[3]=lp[3];               \
        }                                                                         \
        float aPm1_0 = (lane == 0) ? -INFINITY : leftPrev;                        \
        float cv0 = lae2(c0.x + aPrev[0], c0.z + aPm1_0);                         \
        float cv1 = lae2(c1.x + aPrev[1], c1.z + aPrev[0]);                       \
        float cv2 = lae2(c2.x + aPrev[2], c2.z + aPrev[1]);                       \
        float cv3 = lae2(c3.x + aPrev[3], c3.z + aPrev[2]);                       \
        if (lane == 0) cv0 = c0.x + aPrev[0];                                     \
        if (t == 0) {                                                             \
            cv0 = (lane == 0) ? 0.0f : -INFINITY;                                 \
            cv1 = -INFINITY; cv2 = -INFINITY; cv3 = -INFINITY;                    \
        }                                                                         \
        float lc = (lane == 0) ? -INFINITY : leftCur;                             \
        float a0 = lae2(lc + c0.y, cv0);                                          \
        float a1 = lae2(a0 + c1.y, cv1);                                          \
        float a2 = lae2(a1 + c2.y, cv2);                                          \
        float a3 = lae2(a2 + c3.y, cv3);                                          \
        if (active) {                                                             \
            const bool tE = (t == 0) | (t == TT - 1);                             \
            float aCm1[4] = { lc, a0, a1, a2 };                                   \
            float aPm1[4] = { aPm1_0, aPrev[0], aPrev[1], aPrev[2] };             \
            float aP[4]   = { aPrev[0], aPrev[1], aPrev[2], aPrev[3] };           \
            float aA[4]   = { a0, a1, a2, a3 };                                   \
            float4 sv[4]  = { c0, c1, c2, c3 };                                   \
            float4* cp = crow + (size_t)t * VV;                                   \
            _Pragma("unroll")                                                     \
            for (int k = 0; k < 4; ++k) {                                         \
                const bool vE = (k == 0 && lane == 0) || (k == 3 && lane == 63);  \
                float w0 = __expf(aP[k]   + sv[k].x - aA[k]);                     \
                float w1 = __expf(aCm1[k] + sv[k].y - aA[k]);                     \
                float w2 = __expf(aPm1[k] + sv[k].z - aA[k]);                     \
                float4 o;                                                         \
                o.x = tE ? 0.0f : (vE ? 1.0f : w0);                               \
                o.y = vE ? 0.0f : (tE ? 1.0f : w1);                               \
                o.z = (tE || vE) ? 0.0f : w2;                                     \
                o.w = 0.0f;                                                       \
                cp[k] = o;                                                        \
            }                                                                     \
            if ((t == TT - 1) && (lane == 63) && (b == 0)) scalar_out[0] = a3;    \
        }                                                                         \
        aPrev[0]=a0; aPrev[1]=a1; aPrev[2]=a2; aPrev[3]=a3;                       \
        leftPrev = leftCur;                                                       \
        leftCur = __shfl_up(a3, 1);                                               \
        ++s;                                                                      \
    }
#pragma unroll 1
    for (int it = 0; it < 107; ++it) { STEPL(P0); STEPL(P1); STEPL(P2); }
#undef STEPL
}

extern "C" void kernel_launch(void* const* d_in, const int* in_sizes, int n_in,
                              void* d_out, int out_size, void* d_ws, size_t ws_size,
                              hipStream_t stream) {
    const float* logits = (const float*)d_in[0];
    float* out = (float*)d_out;
    const size_t ncell = (size_t)BB * TT * VV;

    float4* scores = (float4*)out;                    // output 0: log_softmax
    float4* counts = (float4*)(out + ncell * 4);      // output 1: expected_counts
    float* scalar_out = out + ncell * 8;              // output 2: alpha[0,-1,-1]

    _Float16* Pd = (_Float16*)d_ws;      // del prob plane  [BB][SLABS][256] fp16
    _Float16* Pi = Pd + PLANE;           // ins prob plane
    _Float16* Pu = Pi + PLANE;           // sub prob plane
    float* Aa = (float*)(Pu + PLANE);    // alpha mantissa  [BB][SLABS][256] fp32
    int*   Ee = (int*)(Aa + PLANE);      // alpha exponent  [BB][SLABS][64]
    int*   prog = Ee + EPLANE;           // per-batch progress [64]

    size_t need = PLANE * 2 * 3 + PLANE * 4 + EPLANE * 4 + 64 * 4;
    if (ws_size >= need) {
        k_prep<<<BB * NSLAB_W, 256, 0, stream>>>((const float4*)logits, scores, Pd, Pi, Pu);
        hipMemsetAsync(prog, 0xFF, 64 * sizeof(int), stream);  // progress = -1
        k_dpcnt<<<32 + NCNT, 256, 0, stream>>>(Pd, Pi, Pu, Aa, Ee, scalar_out, prog, counts);
    } else {
        k_prep_legacy<<<2048, 256, 0, stream>>>((const float4*)logits, scores, (int)ncell);
        k_dp_legacy<<<BB, 64, 0, stream>>>(scores, counts, scalar_out);
    }
}

// Round 15
// 106.902 us; speedup vs baseline: 3.5350x; 3.5350x over previous
//
#include <hip/hip_runtime.h>
#include <math.h>

#define BB 64
#define TT 256
#define VV 256
#define SLABS 321            // slab s = t + v/4 in [0,318]; +2 pad for clamped prefetch
#define SLAB_F (SLABS * 256) // elements per batch per plane = 82176
#define PLANE ((size_t)BB * SLAB_F)       // elements per plane
#define EPLANE ((size_t)BB * SLABS * 64)  // ints in exponent plane
#define NSLAB_W 319          // slabs 0..318 hold at least one valid (t,v)

typedef __attribute__((ext_vector_type(4))) _Float16 half4;

// DPP wave_shr1: lane L <- lane L-1, single VALU op (wave-local; lane 0 keeps
// own value and is always masked by a lane-0 select at the use site).
__device__ __forceinline__ float dpp_shr1_f(float x) {
    return __int_as_float(__builtin_amdgcn_update_dpp(
        __float_as_int(x), __float_as_int(x), 0x138, 0xF, 0xF, false));
}
__device__ __forceinline__ int dpp_shr1_i(int x) {
    return __builtin_amdgcn_update_dpp(x, x, 0x138, 0xF, 0xF, false);
}

// log-domain logaddexp for the legacy fallback only
__device__ __forceinline__ float lae2(float x, float y) {
    float m = fmaxf(x, y);
    float d = x - y;
    return m + __logf(1.0f + __expf(-fabsf(d)));
}

// Kernel 1 (diag-major): one block per (b, slab). Thread j owns v=j, t=s-(j>>2).
// FP16 prob planes (storage only; all math fp32). Invalid-t lanes write prob 0.
__global__ void __launch_bounds__(256) k_prep(const float4* __restrict__ lg,
                                              float4* __restrict__ sc,
                                              _Float16* __restrict__ Dd,
                                              _Float16* __restrict__ Di,
                                              _Float16* __restrict__ Du) {
    int blk = blockIdx.x;
    int b = blk / NSLAB_W;
    int s = blk - b * NSLAB_W;
    int v = threadIdx.x;
    int t = s - (v >> 2);
    bool valid = (t >= 0) && (t < TT);
    int tc = valid ? t : 0;
    size_t ci = ((size_t)b << 16) | ((size_t)tc << 8) | (size_t)v;
    float4 x = lg[ci];
    float m = fmaxf(fmaxf(x.x, x.y), fmaxf(x.z, x.w));
    float e0 = __expf(x.x - m), e1 = __expf(x.y - m);
    float e2 = __expf(x.z - m), e3 = __expf(x.w - m);
    float ssum = e0 + e1 + e2 + e3;
    float l = m + __logf(ssum);
    if (valid) sc[ci] = make_float4(x.x - l, x.y - l, x.z - l, x.w - l);
    float rcp = valid ? (1.0f / ssum) : 0.0f;
    size_t pb = (size_t)b * SLAB_F + ((size_t)s << 8) + v;
    Dd[pb] = (_Float16)(e0 * rcp);
    Di[pb] = (_Float16)(e1 * rcp);
    Du[pb] = (_Float16)(e2 * rcp);
}

// Kernel 2: serial anti-diagonal DP, linear (probability) domain, zero
// transcendentals, DPP cross-lane, 8-deep prefetch ring. ONE wave per CU
// (64 blocks x 64 threads): fp16 planes halved per-wave TA lines (r13), so
// per-CU TA with 2-wave colocation (~205cy/step) now exceeds the 1-wave
// latency floor — r14 A/B. (r14's producer-consumer merge regressed 9x:
// CU-sharing + polling storm + threadfence ring-collapse. Reverted.)
// PER-STEP renorm (r10: deferred renorm underflows — data-dependent spread).
// A stays FP32 (fp16 A would recreate r10's 1/0->NaN).
__global__ void __launch_bounds__(64) k_dp(const _Float16* __restrict__ Pd,
                                           const _Float16* __restrict__ Pi,
                                           const _Float16* __restrict__ Pu,
                                           float* __restrict__ A,
                                           int* __restrict__ Ei,
                                           float* __restrict__ scalar_out) {
    const int b = blockIdx.x;
    const int lane = threadIdx.x;       // 0..63
    const bool l0 = (lane == 0);
    const size_t base = (size_t)b * SLAB_F + (lane << 2);

    const half4* __restrict__ pd = (const half4*)(Pd + base);
    const half4* __restrict__ pi = (const half4*)(Pi + base);
    const half4* __restrict__ pu = (const half4*)(Pu + base);
    float4* __restrict__ pa = (float4*)(A + base);
    int* __restrict__ pe = Ei + (size_t)b * SLABS * 64 + lane;
    const int SS = 64;  // slab stride in half4 units

    // 8-deep prefetch ring (statically indexed via 8x unroll)
    half4 d0,d1,d2,d3,d4,d5,d6,d7;
    half4 i0,i1,i2,i3,i4,i5,i6,i7;
    half4 u0,u1,u2,u3,u4,u5,u6,u7;
    d0 = pd[0*SS]; i0 = pi[0*SS]; u0 = pu[0*SS];
    d1 = pd[1*SS]; i1 = pi[1*SS]; u1 = pu[1*SS];
    d2 = pd[2*SS]; i2 = pi[2*SS]; u2 = pu[2*SS];
    d3 = pd[3*SS]; i3 = pi[3*SS]; u3 = pu[3*SS];
    d4 = pd[4*SS]; i4 = pi[4*SS]; u4 = pu[4*SS];
    d5 = pd[5*SS]; i5 = pi[5*SS]; u5 = pu[5*SS];
    d6 = pd[6*SS]; i6 = pi[6*SS]; u6 = pu[6*SS];
    d7 = pd[7*SS]; i7 = pi[7*SS]; u7 = pu[7*SS];

    float A0 = 0.0f, A1 = 0.0f, A2 = 0.0f, A3 = 0.0f;
    int   E  = 0;
    float LC = 0.0f, LP = 0.0f;   // left neighbor's A3 from steps s-1, s-2
    int   EC = 0,    EP = 0;
    float sA3 = 0.0f;             // saved state at s==318 for scalar_out
    int   sEn = 0;

    int s = 0;

    // FIXUP: t==0 handling (fill only). CLAMP: prefetch clamp (tail only).
    // CAP: scalar capture (tail only). Renorm: EVERY step.
#define STEP(DD, II, UU, FIXUP, CLAMP, CAP)                                       \
    {                                                                             \
        const half4 dl = DD, in = II, su = UU;                                    \
        {                                                                         \
            int sp = s + 8;                                                       \
            if (CLAMP) sp = sp > SLABS - 1 ? SLABS - 1 : sp;                      \
            DD = pd[sp * SS]; II = pi[sp * SS]; UU = pu[sp * SS];                 \
        }                                                                         \
        int E_eff = E;                                                            \
        bool isT0 = false;                                                        \
        if (FIXUP) {                                                              \
            isT0 = (s == lane);                                                   \
            E_eff = isT0 ? (l0 ? 0 : EC) : E;                                     \
        }                                                                         \
        const float lc = l0 ? 0.0f : ldexpf(LC, EC - E_eff);                      \
        const float lp = l0 ? 0.0f : ldexpf(LP, EP - E_eff);                      \
        float X0 = (float)dl.x * A0 + (float)su.x * lp;                           \
        float X1 = (float)dl.y * A1 + (float)su.y * A0;                           \
        float X2 = (float)dl.z * A2 + (float)su.z * A1;                           \
        float X3 = (float)dl.w * A3 + (float)su.w * A2;                           \
        if (FIXUP && isT0) {                                                      \
            X0 = l0 ? 1.0f : 0.0f; X1 = 0.0f; X2 = 0.0f; X3 = 0.0f;               \
        }                                                                         \
        const float iy = (float)in.y, iz = (float)in.z, iw = (float)in.w;         \
        const float B0 = X0;                                                      \
        const float B1 = fmaf(B0, iy, X1);                                        \
        const float B2 = fmaf(B1, iz, X2);                                        \
        const float B3 = fmaf(B2, iw, X3);                                        \
        const float Q0 = (float)in.x;                                             \
        const float Q1 = Q0 * iy;                                                 \
        const float Q2 = Q1 * iz;                                                 \
        const float Q3 = Q2 * iw;                                                 \
        float nA0 = fmaf(lc, Q0, B0);                                             \
        float nA1 = fmaf(lc, Q1, B1);                                             \
        float nA2 = fmaf(lc, Q2, B2);                                             \
        float nA3 = fmaf(lc, Q3, B3);                                             \
        const int eb = (int)((__float_as_uint(nA3) >> 23) & 255u) - 126;          \
        const int En = E_eff + eb;                                                \
        nA3 = ldexpf(nA3, -eb);                                                   \
        nA0 = ldexpf(nA0, -eb);                                                   \
        nA1 = ldexpf(nA1, -eb);                                                   \
        nA2 = ldexpf(nA2, -eb);                                                   \
        LP = LC; EP = EC;                                                         \
        LC = dpp_shr1_f(nA3);                                                     \
        EC = dpp_shr1_i(En);                                                      \
        pa[s * SS] = make_float4(nA0, nA1, nA2, nA3);                             \
        pe[s * 64] = En;                                                          \
        if (CAP && s == TT + 62) { sA3 = nA3; sEn = En; }  /* lane63: t==255 */   \
        A0 = nA0; A1 = nA1; A2 = nA2; A3 = nA3; E = En;                           \
        ++s;                                                                      \
    }

    // fill: s=0..63 — full fixups; no clamp needed (s+8<=71)
#pragma unroll 1
    for (int it = 0; it < 8; ++it) {
        STEP(d0, i0, u0, 1, 0, 0);
        STEP(d1, i1, u1, 1, 0, 0);
        STEP(d2, i2, u2, 1, 0, 0);
        STEP(d3, i3, u3, 1, 0, 0);
        STEP(d4, i4, u4, 1, 0, 0);
        STEP(d5, i5, u5, 1, 0, 0);
        STEP(d6, i6, u6, 1, 0, 0);
        STEP(d7, i7, u7, 1, 0, 0);
    }
    // steady: s=64..311 — no fixup, no clamp (s+8<=319)
#pragma unroll 1
    for (int it = 0; it < 31; ++it) {
        STEP(d0, i0, u0, 0, 0, 0);
        STEP(d1, i1, u1, 0, 0, 0);
        STEP(d2, i2, u2, 0, 0, 0);
        STEP(d3, i3, u3, 0, 0, 0);
        STEP(d4, i4, u4, 0, 0, 0);
        STEP(d5, i5, u5, 0, 0, 0);
        STEP(d6, i6, u6, 0, 0, 0);
        STEP(d7, i7, u7, 0, 0, 0);
    }
    // tail: s=312..319 — clamp + scalar capture
    STEP(d0, i0, u0, 0, 1, 1);
    STEP(d1, i1, u1, 0, 1, 1);
    STEP(d2, i2, u2, 0, 1, 1);
    STEP(d3, i3, u3, 0, 1, 1);
    STEP(d4, i4, u4, 0, 1, 1);
    STEP(d5, i5, u5, 0, 1, 1);
    STEP(d6, i6, u6, 0, 1, 1);
    STEP(d7, i7, u7, 0, 1, 1);
#undef STEP

    if ((b == 0) && (lane == 63))
        scalar_out[0] = logf(sA3) + (float)sEn * 0.6931471805599453f;
}

// Kernel 3 (cell-per-thread, k_prep-style mapping): block=(b,slab), thread j
// owns v=j, t=s-(j>>2). All streams whole-line-group access. Neighbor alphas by
// direct index: left/diag live in slab s / s-1 (v%4!=0) or s-1 / s-2 (v%4==0).
// Interior: norm == alpha, count = prob * (A_nb/A_cell) * 2^(E_nb-E_cell).
__global__ void __launch_bounds__(256) k_counts(const _Float16* __restrict__ Pd,
                                                const _Float16* __restrict__ Pi,
                                                const _Float16* __restrict__ Pu,
                                                const float* __restrict__ A,
                                                const int* __restrict__ Ei,
                                                float4* __restrict__ out) {
    int blk = blockIdx.x;
    int b = blk / NSLAB_W;
    int s = blk - b * NSLAB_W;
    int v = threadIdx.x;
    int g = v >> 2;
    int t = s - g;
    if ((t < 0) | (t >= TT)) return;

    size_t ab = (size_t)b * SLAB_F;
    size_t ebp = (size_t)b * SLABS * 64;
    int sm1 = s > 0 ? s - 1 : 0;   // in-bounds; masked by tE/vE where invalid
    int sm2 = s > 1 ? s - 2 : 0;
    int vm = v ? v - 1 : 0;
    int gm = g ? g - 1 : 0;
    bool v4 = (v & 3) == 0;

    float pD = (float)Pd[ab + ((size_t)s << 8) + v];
    float pI = (float)Pi[ab + ((size_t)s << 8) + v];
    float pU = (float)Pu[ab + ((size_t)s << 8) + v];
    float AA = A[ab + ((size_t)s   << 8) + v];
    float AU = A[ab + ((size_t)sm1 << 8) + v];
    int   EA = Ei[ebp + s   * 64 + g];
    int   EU = Ei[ebp + sm1 * 64 + g];
    float AL = v4 ? A[ab + ((size_t)sm1 << 8) + vm] : A[ab + ((size_t)s   << 8) + vm];
    int   EL = v4 ? Ei[ebp + sm1 * 64 + gm] : EA;
    float AD = v4 ? A[ab + ((size_t)sm2 << 8) + vm] : A[ab + ((size_t)sm1 << 8) + vm];
    int   ED = v4 ? Ei[ebp + sm2 * 64 + gm] : EU;

    bool tE = (t == 0) | (t == TT - 1);
    bool vE = (v == 0) | (v == VV - 1);
    float inv = 1.0f / AA;
    float w0 = ldexpf(pD * AU * inv, EU - EA);
    float w1 = ldexpf(pI * AL * inv, EL - EA);
    float w2 = ldexpf(pU * AD * inv, ED - EA);
    float4 o;
    o.x = tE ? 0.0f : (vE ? 1.0f : w0);
    o.y = vE ? 0.0f : (tE ? 1.0f : w1);
    o.z = (tE | vE) ? 0.0f : w2;
    o.w = 0.0f;
    out[((size_t)b << 16) | ((size_t)t << 8) | (size_t)v] = o;
}

// Fallbacks for tiny ws: canonical log_softmax + fused scattered log-domain DP.
__global__ void k_prep_legacy(const float4* __restrict__ lg, float4* __restrict__ sc, int n) {
    int i = blockIdx.x * blockDim.x + threadIdx.x;
    int st = gridDim.x * blockDim.x;
    for (; i < n; i += st) {
        float4 x = lg[i];
        float m = fmaxf(fmaxf(x.x, x.y), fmaxf(x.z, x.w));
        float s = __expf(x.x - m) + __expf(x.y - m) + __expf(x.z - m) + __expf(x.w - m);
        float l = m + __logf(s);
        sc[i] = make_float4(x.x - l, x.y - l, x.z - l, x.w - l);
    }
}
__global__ void __launch_bounds__(64) k_dp_legacy(const float4* __restrict__ scores,
                                                  float4* __restrict__ counts,
                                                  float* __restrict__ scalar_out) {
    const int b = blockIdx.x;
    const int lane = threadIdx.x;
    const int v0 = lane << 2;
    const float4* __restrict__ srow = scores + ((size_t)b * TT * VV + v0);
    float4* __restrict__ crow = counts + ((size_t)b * TT * VV + v0);
    float4 P0[4], P1[4], P2[4];
    {
        int r; const float4* p;
        r = 0 - lane; r = r < 0 ? 0 : r; p = srow + (size_t)r * VV;
        P0[0]=p[0]; P0[1]=p[1]; P0[2]=p[2]; P0[3]=p[3];
        r = 1 - lane; r = r < 0 ? 0 : r; p = srow + (size_t)r * VV;
        P1[0]=p[0]; P1[1]=p[1]; P1[2]=p[2]; P1[3]=p[3];
        r = 2 - lane; r = r < 0 ? 0 : r; p = srow + (size_t)r * VV;
        P2[0]=p[0]; P2[1]=p[1]; P2[2]=p[2]; P2[3]=p[3];
    }
    float aPrev[4] = { -INFINITY, -INFINITY, -INFINITY, -INFINITY };
    float leftPrev = -INFINITY, leftCur = -INFINITY;
    int s = 0;
#define STEPL(BUF)                                                                \
    {                                                                             \
        const int t = s - lane;                                                   \
        const bool active = (t >= 0) && (t < TT);                                 \
        float4 c0 = BUF[0], c1 = BUF[1], c2 = BUF[2], c3 = BUF[3];                \
        {                                                                         \
            int tp = t + 3; tp = tp < 0 ? 0 : tp; tp = tp > TT - 1 ? TT - 1 : tp; \
            const float4* lp = srow + (size_t)tp * VV;                            \
            BUF[0]=lp[0]; BUF[1]=lp[1]; BUF[2]=lp[2]; BUF[3]=lp[3];               \
        }                                                                         \
        float aPm1_0 = (lane == 0) ? -INFINITY : leftPrev;                        \
        float cv0 = lae2(c0.x + aPrev[0], c0.z + aPm1_0);                         \
        float cv1 = lae2(c1.x + aPrev[1], c1.z + aPrev[0]);                       \
        float cv2 = lae2(c2.x + aPrev[2], c2.z + aPrev[1]);                       \
        float cv3 = lae2(c3.x + aPrev[3], c3.z + aPrev[2]);                       \
        if (lane == 0) cv0 = c0.x + aPrev[0];                                     \
        if (t == 0) {                                                             \
            cv0 = (lane == 0) ? 0.0f : -INFINITY;                                 \
            cv1 = -INFINITY; cv2 = -INFINITY; cv3 = -INFINITY;                    \
        }                                                                         \
        float lc = (lane == 0) ? -INFINITY : leftCur;                             \
        float a0 = lae2(lc + c0.y, cv0);                                          \
        float a1 = lae2(a0 + c1.y, cv1);                                          \
        float a2 = lae2(a1 + c2.y, cv2);                                          \
        float a3 = lae2(a2 + c3.y, cv3);                                          \
        if (active) {                                                             \
            const bool tE = (t == 0) | (t == TT - 1);                             \
            float aCm1[4] = { lc, a0, a1, a2 };                                   \
            float aPm1[4] = { aPm1_0, aPrev[0], aPrev[1], aPrev[2] };             \
            float aP[4]   = { aPrev[0], aPrev[1], aPrev[2], aPrev[3] };           \
            float aA[4]   = { a0, a1, a2, a3 };                                   \
            float4 sv[4]  = { c0, c1, c2, c3 };                                   \
            float4* cp = crow + (size_t)t * VV;                                   \
            _Pragma("unroll")                                                     \
            for (int k = 0; k < 4; ++k) {                                         \
                const bool vE = (k == 0 && lane == 0) || (k == 3 && lane == 63);  \
                float w0 = __expf(aP[k]   + sv[k].x - aA[k]);                     \
                float w1 = __expf(aCm1[k] + sv[k].y - aA[k]);                     \
                float w2 = __expf(aPm1[k] + sv[k].z - aA[k]);                     \
                float4 o;                                                         \
                o.x = tE ? 0.0f : (vE ? 1.0f : w0);                               \
                o.y = vE ? 0.0f : (tE ? 1.0f : w1);                               \
                o.z = (tE || vE) ? 0.0f : w2;                                     \
                o.w = 0.0f;                                                       \
                cp[k] = o;                                                        \
            }                                                                     \
            if ((t == TT - 1) && (lane == 63) && (b == 0)) scalar_out[0] = a3;    \
        }                                                                         \
        aPrev[0]=a0; aPrev[1]=a1; aPrev[2]=a2; aPrev[3]=a3;                       \
        leftPrev = leftCur;                                                       \
        leftCur = __shfl_up(a3, 1);                                               \
        ++s;                                                                      \
    }
#pragma unroll 1
    for (int it = 0; it < 107; ++it) { STEPL(P0); STEPL(P1); STEPL(P2); }
#undef STEPL
}

extern "C" void kernel_launch(void* const* d_in, const int* in_sizes, int n_in,
                              void* d_out, int out_size, void* d_ws, size_t ws_size,
                              hipStream_t stream) {
    const float* logits = (const float*)d_in[0];
    float* out = (float*)d_out;
    const size_t ncell = (size_t)BB * TT * VV;

    float4* scores = (float4*)out;                    // output 0: log_softmax
    float4* counts = (float4*)(out + ncell * 4);      // output 1: expected_counts
    float* scalar_out = out + ncell * 8;              // output 2: alpha[0,-1,-1]

    _Float16* Pd = (_Float16*)d_ws;      // del prob plane  [BB][SLABS][256] fp16
    _Float16* Pi = Pd + PLANE;           // ins prob plane
    _Float16* Pu = Pi + PLANE;           // sub prob plane
    float* Aa = (float*)(Pu + PLANE);    // alpha mantissa  [BB][SLABS][256] fp32
    int*   Ee = (int*)(Aa + PLANE);      // alpha exponent  [BB][SLABS][64]

    size_t need = PLANE * 2 * 3 + PLANE * 4 + EPLANE * 4;
    if (ws_size >= need) {
        k_prep<<<BB * NSLAB_W, 256, 0, stream>>>((const float4*)logits, scores, Pd, Pi, Pu);
        k_dp<<<BB, 64, 0, stream>>>(Pd, Pi, Pu, Aa, Ee, scalar_out);
        k_counts<<<BB * NSLAB_W, 256, 0, stream>>>(Pd, Pi, Pu, Aa, Ee, counts);
    } else {
        k_prep_legacy<<<2048, 256, 0, stream>>>((const float4*)logits, scores, (int)ncell);
        k_dp_legacy<<<BB, 64, 0, stream>>>(scores, counts, scalar_out);
    }
}

// Round 16
// 105.322 us; speedup vs baseline: 3.5881x; 1.0150x over previous
//
#include <hip/hip_runtime.h>
#include <math.h>

#define BB 64
#define TT 256
#define VV 256
#define SLABS 321            // slab s = t + v/4 in [0,318]; +2 pad for clamped prefetch
#define SLAB_F (SLABS * 256) // elements per batch per plane = 82176
#define PLANE ((size_t)BB * SLAB_F)       // elements per plane
#define NSLAB_W 319          // slabs 0..318 hold at least one valid (t,v)

typedef __attribute__((ext_vector_type(4))) _Float16 half4;

// DPP wave_shr1: lane L <- lane L-1, single VALU op (wave-local; lane 0 keeps
// own value and is always masked by a lane-0 select at the use site).
__device__ __forceinline__ float dpp_shr1_f(float x) {
    return __int_as_float(__builtin_amdgcn_update_dpp(
        __float_as_int(x), __float_as_int(x), 0x138, 0xF, 0xF, false));
}
__device__ __forceinline__ int dpp_shr1_i(int x) {
    return __builtin_amdgcn_update_dpp(x, x, 0x138, 0xF, 0xF, false);
}

// log-domain logaddexp for the legacy fallback only
__device__ __forceinline__ float lae2(float x, float y) {
    float m = fmaxf(x, y);
    float d = x - y;
    return m + __logf(1.0f + __expf(-fabsf(d)));
}

// Kernel 1 (diag-major): one block per (b, slab). Thread j owns v=j, t=s-(j>>2).
// FP16 prob planes (storage only; all math fp32). Invalid-t lanes write prob 0.
__global__ void __launch_bounds__(256) k_prep(const float4* __restrict__ lg,
                                              float4* __restrict__ sc,
                                              _Float16* __restrict__ Dd,
                                              _Float16* __restrict__ Di,
                                              _Float16* __restrict__ Du) {
    int blk = blockIdx.x;
    int b = blk / NSLAB_W;
    int s = blk - b * NSLAB_W;
    int v = threadIdx.x;
    int t = s - (v >> 2);
    bool valid = (t >= 0) && (t < TT);
    int tc = valid ? t : 0;
    size_t ci = ((size_t)b << 16) | ((size_t)tc << 8) | (size_t)v;
    float4 x = lg[ci];
    float m = fmaxf(fmaxf(x.x, x.y), fmaxf(x.z, x.w));
    float e0 = __expf(x.x - m), e1 = __expf(x.y - m);
    float e2 = __expf(x.z - m), e3 = __expf(x.w - m);
    float ssum = e0 + e1 + e2 + e3;
    float l = m + __logf(ssum);
    if (valid) sc[ci] = make_float4(x.x - l, x.y - l, x.z - l, x.w - l);
    float rcp = valid ? (1.0f / ssum) : 0.0f;
    size_t pb = (size_t)b * SLAB_F + ((size_t)s << 8) + v;
    Dd[pb] = (_Float16)(e0 * rcp);
    Di[pb] = (_Float16)(e1 * rcp);
    Du[pb] = (_Float16)(e2 * rcp);
}

// Kernel 2: serial anti-diagonal DP, linear domain, zero transcendentals,
// DPP cross-lane, 8-deep prefetch ring, ONE wave per CU (r15 A/B).
// NEW (r16): count weights FUSED — all neighbor alphas are live registers
// (AU=A_old_k, AL=(k==0? lc : nA_{k-1}), common exponent pre-renorm), so
// w0=pD*AU/nA, w1=pI*AL/nA via fast rcp; Σw=1 for interior (norm==alpha)
// so only w0,w1 stored (2 fp16 planes, 16 store-lines vs 17 for A+E).
// A/E planes deleted. Any rcp-subnormal inf/NaN is clamped in k_wperm
// (worst case maps to <=1.0, threshold 2.24). PER-STEP renorm (r10 lesson).
__global__ void __launch_bounds__(64) k_dp(const _Float16* __restrict__ Pd,
                                           const _Float16* __restrict__ Pi,
                                           const _Float16* __restrict__ Pu,
                                           _Float16* __restrict__ W0,
                                           _Float16* __restrict__ W1,
                                           float* __restrict__ scalar_out) {
    const int b = blockIdx.x;
    const int lane = threadIdx.x;       // 0..63
    const bool l0 = (lane == 0);
    const size_t base = (size_t)b * SLAB_F + (lane << 2);

    const half4* __restrict__ pd = (const half4*)(Pd + base);
    const half4* __restrict__ pi = (const half4*)(Pi + base);
    const half4* __restrict__ pu = (const half4*)(Pu + base);
    half4* __restrict__ pw0 = (half4*)(W0 + base);
    half4* __restrict__ pw1 = (half4*)(W1 + base);
    const int SS = 64;  // slab stride in half4 units

    // 8-deep prefetch ring (statically indexed via 8x unroll)
    half4 d0,d1,d2,d3,d4,d5,d6,d7;
    half4 i0,i1,i2,i3,i4,i5,i6,i7;
    half4 u0,u1,u2,u3,u4,u5,u6,u7;
    d0 = pd[0*SS]; i0 = pi[0*SS]; u0 = pu[0*SS];
    d1 = pd[1*SS]; i1 = pi[1*SS]; u1 = pu[1*SS];
    d2 = pd[2*SS]; i2 = pi[2*SS]; u2 = pu[2*SS];
    d3 = pd[3*SS]; i3 = pi[3*SS]; u3 = pu[3*SS];
    d4 = pd[4*SS]; i4 = pi[4*SS]; u4 = pu[4*SS];
    d5 = pd[5*SS]; i5 = pi[5*SS]; u5 = pu[5*SS];
    d6 = pd[6*SS]; i6 = pi[6*SS]; u6 = pu[6*SS];
    d7 = pd[7*SS]; i7 = pi[7*SS]; u7 = pu[7*SS];

    float A0 = 0.0f, A1 = 0.0f, A2 = 0.0f, A3 = 0.0f;
    int   E  = 0;
    float LC = 0.0f, LP = 0.0f;   // left neighbor's A3 from steps s-1, s-2
    int   EC = 0,    EP = 0;
    float sA3 = 0.0f;             // saved state at s==318 for scalar_out
    int   sEn = 0;

    int s = 0;

    // FIXUP: t==0 handling (fill only). CLAMP: prefetch clamp (tail only).
    // CAP: scalar capture (tail only). Renorm: EVERY step.
    // w stored PRE-renorm: A_old, lc, nA all at exponent E_eff (isT0 lanes'
    // mismatch is tE-masked in k_wperm; t<0 garbage never read).
#define STEP(DD, II, UU, FIXUP, CLAMP, CAP)                                       \
    {                                                                             \
        const half4 dl = DD, in = II, su = UU;                                    \
        {                                                                         \
            int sp = s + 8;                                                       \
            if (CLAMP) sp = sp > SLABS - 1 ? SLABS - 1 : sp;                      \
            DD = pd[sp * SS]; II = pi[sp * SS]; UU = pu[sp * SS];                 \
        }                                                                         \
        int E_eff = E;                                                            \
        bool isT0 = false;                                                        \
        if (FIXUP) {                                                              \
            isT0 = (s == lane);                                                   \
            E_eff = isT0 ? (l0 ? 0 : EC) : E;                                     \
        }                                                                         \
        const float lc = l0 ? 0.0f : ldexpf(LC, EC - E_eff);                      \
        const float lp = l0 ? 0.0f : ldexpf(LP, EP - E_eff);                      \
        float X0 = (float)dl.x * A0 + (float)su.x * lp;                           \
        float X1 = (float)dl.y * A1 + (float)su.y * A0;                           \
        float X2 = (float)dl.z * A2 + (float)su.z * A1;                           \
        float X3 = (float)dl.w * A3 + (float)su.w * A2;                           \
        if (FIXUP && isT0) {                                                      \
            X0 = l0 ? 1.0f : 0.0f; X1 = 0.0f; X2 = 0.0f; X3 = 0.0f;               \
        }                                                                         \
        const float iy = (float)in.y, iz = (float)in.z, iw = (float)in.w;         \
        const float B0 = X0;                                                      \
        const float B1 = fmaf(B0, iy, X1);                                        \
        const float B2 = fmaf(B1, iz, X2);                                        \
        const float B3 = fmaf(B2, iw, X3);                                        \
        const float Q0 = (float)in.x;                                             \
        const float Q1 = Q0 * iy;                                                 \
        const float Q2 = Q1 * iz;                                                 \
        const float Q3 = Q2 * iw;                                                 \
        float nA0 = fmaf(lc, Q0, B0);                                             \
        float nA1 = fmaf(lc, Q1, B1);                                             \
        float nA2 = fmaf(lc, Q2, B2);                                             \
        float nA3 = fmaf(lc, Q3, B3);                                             \
        /* fused count weights (pre-renorm, common exponent) */                   \
        const float r0 = __builtin_amdgcn_rcpf(nA0);                              \
        const float r1 = __builtin_amdgcn_rcpf(nA1);                              \
        const float r2 = __builtin_amdgcn_rcpf(nA2);                              \
        const float r3 = __builtin_amdgcn_rcpf(nA3);                              \
        half4 h0, h1;                                                             \
        h0.x = (_Float16)((float)dl.x * A0 * r0);                                 \
        h0.y = (_Float16)((float)dl.y * A1 * r1);                                 \
        h0.z = (_Float16)((float)dl.z * A2 * r2);                                 \
        h0.w = (_Float16)((float)dl.w * A3 * r3);                                 \
        h1.x = (_Float16)(Q0 * lc * r0);                                          \
        h1.y = (_Float16)(iy * nA0 * r1);                                         \
        h1.z = (_Float16)(iz * nA1 * r2);                                         \
        h1.w = (_Float16)(iw * nA2 * r3);                                         \
        pw0[s * SS] = h0;                                                         \
        pw1[s * SS] = h1;                                                         \
        const int eb = (int)((__float_as_uint(nA3) >> 23) & 255u) - 126;          \
        const int En = E_eff + eb;                                                \
        nA3 = ldexpf(nA3, -eb);                                                   \
        nA0 = ldexpf(nA0, -eb);                                                   \
        nA1 = ldexpf(nA1, -eb);                                                   \
        nA2 = ldexpf(nA2, -eb);                                                   \
        LP = LC; EP = EC;                                                         \
        LC = dpp_shr1_f(nA3);                                                     \
        EC = dpp_shr1_i(En);                                                      \
        if (CAP && s == TT + 62) { sA3 = nA3; sEn = En; }  /* lane63: t==255 */   \
        A0 = nA0; A1 = nA1; A2 = nA2; A3 = nA3; E = En;                           \
        ++s;                                                                      \
    }

    // fill: s=0..63 — full fixups; no clamp needed (s+8<=71)
#pragma unroll 1
    for (int it = 0; it < 8; ++it) {
        STEP(d0, i0, u0, 1, 0, 0);
        STEP(d1, i1, u1, 1, 0, 0);
        STEP(d2, i2, u2, 1, 0, 0);
        STEP(d3, i3, u3, 1, 0, 0);
        STEP(d4, i4, u4, 1, 0, 0);
        STEP(d5, i5, u5, 1, 0, 0);
        STEP(d6, i6, u6, 1, 0, 0);
        STEP(d7, i7, u7, 1, 0, 0);
    }
    // steady: s=64..311 — no fixup, no clamp (s+8<=319)
#pragma unroll 1
    for (int it = 0; it < 31; ++it) {
        STEP(d0, i0, u0, 0, 0, 0);
        STEP(d1, i1, u1, 0, 0, 0);
        STEP(d2, i2, u2, 0, 0, 0);
        STEP(d3, i3, u3, 0, 0, 0);
        STEP(d4, i4, u4, 0, 0, 0);
        STEP(d5, i5, u5, 0, 0, 0);
        STEP(d6, i6, u6, 0, 0, 0);
        STEP(d7, i7, u7, 0, 0, 0);
    }
    // tail: s=312..319 — clamp + scalar capture
    STEP(d0, i0, u0, 0, 1, 1);
    STEP(d1, i1, u1, 0, 1, 1);
    STEP(d2, i2, u2, 0, 1, 1);
    STEP(d3, i3, u3, 0, 1, 1);
    STEP(d4, i4, u4, 0, 1, 1);
    STEP(d5, i5, u5, 0, 1, 1);
    STEP(d6, i6, u6, 0, 1, 1);
    STEP(d7, i7, u7, 0, 1, 1);
#undef STEP

    if ((b == 0) && (lane == 63))
        scalar_out[0] = logf(sA3) + (float)sEn * 0.6931471805599453f;
}

// Kernel 3: pure permute. Cell-per-thread k_prep mapping: block=(b,slab),
// thread j owns v=j, t=s-(j>>2). Reads w0,w1 (fp16 diag planes), w2=1-w0-w1
// (Σw=1 for interior since norm==alpha), clamps [0,1] (absorbs any rcp corner
// inf/NaN), applies the r2-validated edge masks, writes canonical counts.
__global__ void __launch_bounds__(256) k_wperm(const _Float16* __restrict__ W0,
                                               const _Float16* __restrict__ W1,
                                               float4* __restrict__ out) {
    int blk = blockIdx.x;
    int b = blk / NSLAB_W;
    int s = blk - b * NSLAB_W;
    int v = threadIdx.x;
    int g = v >> 2;
    int t = s - g;
    if ((t < 0) | (t >= TT)) return;

    size_t pb = (size_t)b * SLAB_F + ((size_t)s << 8) + v;
    float w0 = (float)W0[pb];
    float w1 = (float)W1[pb];
    w0 = fminf(fmaxf(w0, 0.0f), 1.0f);
    w1 = fminf(fmaxf(w1, 0.0f), 1.0f);
    float w2 = fmaxf(0.0f, 1.0f - w0 - w1);

    bool tE = (t == 0) | (t == TT - 1);
    bool vE = (v == 0) | (v == VV - 1);
    float4 o;
    o.x = tE ? 0.0f : (vE ? 1.0f : w0);
    o.y = vE ? 0.0f : (tE ? 1.0f : w1);
    o.z = (tE | vE) ? 0.0f : w2;
    o.w = 0.0f;
    out[((size_t)b << 16) | ((size_t)t << 8) | (size_t)v] = o;
}

// Fallbacks for tiny ws: canonical log_softmax + fused scattered log-domain DP.
__global__ void k_prep_legacy(const float4* __restrict__ lg, float4* __restrict__ sc, int n) {
    int i = blockIdx.x * blockDim.x + threadIdx.x;
    int st = gridDim.x * blockDim.x;
    for (; i < n; i += st) {
        float4 x = lg[i];
        float m = fmaxf(fmaxf(x.x, x.y), fmaxf(x.z, x.w));
        float s = __expf(x.x - m) + __expf(x.y - m) + __expf(x.z - m) + __expf(x.w - m);
        float l = m + __logf(s);
        sc[i] = make_float4(x.x - l, x.y - l, x.z - l, x.w - l);
    }
}
__global__ void __launch_bounds__(64) k_dp_legacy(const float4* __restrict__ scores,
                                                  float4* __restrict__ counts,
                                                  float* __restrict__ scalar_out) {
    const int b = blockIdx.x;
    const int lane = threadIdx.x;
    const int v0 = lane << 2;
    const float4* __restrict__ srow = scores + ((size_t)b * TT * VV + v0);
    float4* __restrict__ crow = counts + ((size_t)b * TT * VV + v0);
    float4 P0[4], P1[4], P2[4];
    {
        int r; const float4* p;
        r = 0 - lane; r = r < 0 ? 0 : r; p = srow + (size_t)r * VV;
        P0[0]=p[0]; P0[1]=p[1]; P0[2]=p[2]; P0[3]=p[3];
        r = 1 - lane; r = r < 0 ? 0 : r; p = srow + (size_t)r * VV;
        P1[0]=p[0]; P1[1]=p[1]; P1[2]=p[2]; P1[3]=p[3];
        r = 2 - lane; r = r < 0 ? 0 : r; p = srow + (size_t)r * VV;
        P2[0]=p[0]; P2[1]=p[1]; P2[2]=p[2]; P2[3]=p[3];
    }
    float aPrev[4] = { -INFINITY, -INFINITY, -INFINITY, -INFINITY };
    float leftPrev = -INFINITY, leftCur = -INFINITY;
    int s = 0;
#define STEPL(BUF)                                                                \
    {                                                                             \
        const int t = s - lane;                                                   \
        const bool active = (t >= 0) && (t < TT);                                 \
        float4 c0 = BUF[0], c1 = BUF[1], c2 = BUF[2], c3 = BUF[3];                \
        {                                                                         \
            int tp = t + 3; tp = tp < 0 ? 0 : tp; tp = tp > TT - 1 ? TT - 1 : tp; \
            const float4* lp = srow + (size_t)tp * VV;                            \
            BUF[0]=lp[0]; BUF[1]=lp[1]; BUF[2]=lp[2]; BUF[3]=lp[3];               \
        }                                                                         \
        float aPm1_0 = (lane == 0) ? -INFINITY : leftPrev;                        \
        float cv0 = lae2(c0.x + aPrev[0], c0.z + aPm1_0);                         \
        float cv1 = lae2(c1.x + aPrev[1], c1.z + aPrev[0]);                       \
        float cv2 = lae2(c2.x + aPrev[2], c2.z + aPrev[1]);                       \
        float cv3 = lae2(c3.x + aPrev[3], c3.z + aPrev[2]);                       \
        if (lane == 0) cv0 = c0.x + aPrev[0];                                     \
        if (t == 0) {                                                             \
            cv0 = (lane == 0) ? 0.0f : -INFINITY;                                 \
            cv1 = -INFINITY; cv2 = -INFINITY; cv3 = -INFINITY;                    \
        }                                                                         \
        float lc = (lane == 0) ? -INFINITY : leftCur;                             \
        float a0 = lae2(lc + c0.y, cv0);                                          \
        float a1 = lae2(a0 + c1.y, cv1);                                          \
        float a2 = lae2(a1 + c2.y, cv2);                                          \
        float a3 = lae2(a2 + c3.y, cv3);                                          \
        if (active) {                                                             \
            const bool tE = (t == 0) | (t == TT - 1);                             \
            float aCm1[4] = { lc, a0, a1, a2 };                                   \
            float aPm1[4] = { aPm1_0, aPrev[0], aPrev[1], aPrev[2] };             \
            float aP[4]   = { aPrev[0], aPrev[1], aPrev[2], aPrev[3] };           \
            float aA[4]   = { a0, a1, a2, a3 };                                   \
            float4 sv[4]  = { c0, c1, c2, c3 };                                   \
            float4* cp = crow + (size_t)t * VV;                                   \
            _Pragma("unroll")                                                     \
            for (int k = 0; k < 4; ++k) {                                         \
                const bool vE = (k == 0 && lane == 0) || (k == 3 && lane == 63);  \
                float w0 = __expf(aP[k]   + sv[k].x - aA[k]);                     \
                float w1 = __expf(aCm1[k] + sv[k].y - aA[k]);                     \
                float w2 = __expf(aPm1[k] + sv[k].z - aA[k]);                     \
                float4 o;                                                         \
                o.x = tE ? 0.0f : (vE ? 1.0f : w0);                               \
                o.y = vE ? 0.0f : (tE ? 1.0f : w1);                               \
                o.z = (tE || vE) ? 0.0f : w2;                                     \
                o.w = 0.0f;                                                       \
                cp[k] = o;                                                        \
            }                                                                     \
            if ((t == TT - 1) && (lane == 63) && (b == 0)) scalar_out[0] = a3;    \
        }                                                                         \
        aPrev[0]=a0; aPrev[1]=a1; aPrev[2]=a2; aPrev[3]=a3;                       \
        leftPrev = leftCur;                                                       \
        leftCur = __shfl_up(a3, 1);                                               \
        ++s;                                                                      \
    }
#pragma unroll 1
    for (int it = 0; it < 107; ++it) { STEPL(P0); STEPL(P1); STEPL(P2); }
#undef STEPL
}

extern "C" void kernel_launch(void* const* d_in, const int* in_sizes, int n_in,
                              void* d_out, int out_size, void* d_ws, size_t ws_size,
                              hipStream_t stream) {
    const float* logits = (const float*)d_in[0];
    float* out = (float*)d_out;
    const size_t ncell = (size_t)BB * TT * VV;

    float4* scores = (float4*)out;                    // output 0: log_softmax
    float4* counts = (float4*)(out + ncell * 4);      // output 1: expected_counts
    float* scalar_out = out + ncell * 8;              // output 2: alpha[0,-1,-1]

    _Float16* Pd = (_Float16*)d_ws;      // del prob plane  [BB][SLABS][256] fp16
    _Float16* Pi = Pd + PLANE;           // ins prob plane
    _Float16* Pu = Pi + PLANE;           // sub prob plane
    _Float16* W0 = Pu + PLANE;           // del weight plane (fp16)
    _Float16* W1 = W0 + PLANE;           // ins weight plane (fp16)

    size_t need = PLANE * 2 * 5;
    if (ws_size >= need) {
        k_prep<<<BB * NSLAB_W, 256, 0, stream>>>((const float4*)logits, scores, Pd, Pi, Pu);
        k_dp<<<BB, 64, 0, stream>>>(Pd, Pi, Pu, W0, W1, scalar_out);
        k_wperm<<<BB * NSLAB_W, 256, 0, stream>>>(W0, W1, counts);
    } else {
        k_prep_legacy<<<2048, 256, 0, stream>>>((const float4*)logits, scores, (int)ncell);
        k_dp_legacy<<<BB, 64, 0, stream>>>(scores, counts, scalar_out);
    }
}

// Round 17
// 105.230 us; speedup vs baseline: 3.5912x; 1.0009x over previous
//
#include <hip/hip_runtime.h>
#include <math.h>

#define BB 64
#define TT 256
#define VV 256
#define SLABS 321            // slab s = t + v/4 in [0,318]; +2 pad for clamped prefetch
#define SLAB_F (SLABS * 256) // cells per batch per plane = 82176
#define PLANE ((size_t)BB * SLAB_F)       // cells per plane
#define NSLAB_W 319          // slabs 0..318 hold at least one valid (t,v)

typedef __attribute__((ext_vector_type(4))) _Float16 half4;
typedef __attribute__((ext_vector_type(8))) _Float16 half8;

// DPP wave_shr1: lane L <- lane L-1, single VALU op (wave-local; lane 0 keeps
// own value and is always masked by a lane-0 select at the use site).
__device__ __forceinline__ float dpp_shr1_f(float x) {
    return __int_as_float(__builtin_amdgcn_update_dpp(
        __float_as_int(x), __float_as_int(x), 0x138, 0xF, 0xF, false));
}
__device__ __forceinline__ int dpp_shr1_i(int x) {
    return __builtin_amdgcn_update_dpp(x, x, 0x138, 0xF, 0xF, false);
}

// log-domain logaddexp for the legacy fallback only
__device__ __forceinline__ float lae2(float x, float y) {
    float m = fmaxf(x, y);
    float d = x - y;
    return m + __logf(1.0f + __expf(-fabsf(d)));
}

// Kernel 1 (diag-major): one block per (b, slab). Thread j owns v=j, t=s-(j>>2).
// del/sub probs packed as OCP fp8 e4m3 pairs (one ushort/cell, HW cvt);
// ins prob stays fp16 (drives the row cumulative Q-chain + scalar — most
// error-sensitive). All math fp32. Invalid-t lanes write prob 0.
// Self-consistency: dp derives weights from these SAME quantized probs, so
// Σw=1 and w∈[0,1] hold by construction; only the ratio vs reference moves.
__global__ void __launch_bounds__(256) k_prep(const float4* __restrict__ lg,
                                              float4* __restrict__ sc,
                                              unsigned short* __restrict__ PDU,
                                              _Float16* __restrict__ Pi) {
    int blk = blockIdx.x;
    int b = blk / NSLAB_W;
    int s = blk - b * NSLAB_W;
    int v = threadIdx.x;
    int t = s - (v >> 2);
    bool valid = (t >= 0) && (t < TT);
    int tc = valid ? t : 0;
    size_t ci = ((size_t)b << 16) | ((size_t)tc << 8) | (size_t)v;
    float4 x = lg[ci];
    float m = fmaxf(fmaxf(x.x, x.y), fmaxf(x.z, x.w));
    float e0 = __expf(x.x - m), e1 = __expf(x.y - m);
    float e2 = __expf(x.z - m), e3 = __expf(x.w - m);
    float ssum = e0 + e1 + e2 + e3;
    float l = m + __logf(ssum);
    if (valid) sc[ci] = make_float4(x.x - l, x.y - l, x.z - l, x.w - l);
    float rcp = valid ? (1.0f / ssum) : 0.0f;
    size_t pb = (size_t)b * SLAB_F + ((size_t)s << 8) + v;
    int pk = __builtin_amdgcn_cvt_pk_fp8_f32(e0 * rcp, e2 * rcp, 0, false);
    PDU[pb] = (unsigned short)pk;          // byte0 = del, byte1 = sub
    Pi[pb] = (_Float16)(e1 * rcp);
}

// Kernel 2: serial anti-diagonal DP, linear domain, zero transcendentals,
// DPP cross-lane, 8-deep prefetch ring, ONE wave per CU (r15 A/B), fused
// count weights (r16). r17: fp8-packed del/sub plane -> ring loads 3 instr/
// 24 lines -> 2 instr/16 lines; decode via v_cvt_f32_fp8 (same cvt count as
// the fp16 converts it replaces); W0/W1 merged into ONE half8 16B store.
// PER-STEP renorm (r10: deferred renorm underflows). r14 lesson: no dynamic
// cross-block gating. isT0 lanes' w garbage is tE-masked in k_wperm.
__global__ void __launch_bounds__(64) k_dp(const unsigned short* __restrict__ PDU,
                                           const _Float16* __restrict__ Pi,
                                           _Float16* __restrict__ W,
                                           float* __restrict__ scalar_out) {
    const int b = blockIdx.x;
    const int lane = threadIdx.x;       // 0..63
    const bool l0 = (lane == 0);
    const size_t cellbase = (size_t)b * SLAB_F + (lane << 2);

    const uint2* __restrict__ pdu = (const uint2*)(PDU + cellbase);
    const half4* __restrict__ pi = (const half4*)(Pi + cellbase);
    half8* __restrict__ pw = (half8*)(W + (size_t)b * SLABS * 512) + lane;
    const int SS = 64;  // slab stride: 256 cells = 64 uint2 = 64 half4

    // 8-deep prefetch ring (statically indexed via 8x unroll)
    uint2 m0,m1,m2,m3,m4,m5,m6,m7;
    half4 i0,i1,i2,i3,i4,i5,i6,i7;
    m0 = pdu[0*SS]; i0 = pi[0*SS];
    m1 = pdu[1*SS]; i1 = pi[1*SS];
    m2 = pdu[2*SS]; i2 = pi[2*SS];
    m3 = pdu[3*SS]; i3 = pi[3*SS];
    m4 = pdu[4*SS]; i4 = pi[4*SS];
    m5 = pdu[5*SS]; i5 = pi[5*SS];
    m6 = pdu[6*SS]; i6 = pi[6*SS];
    m7 = pdu[7*SS]; i7 = pi[7*SS];

    float A0 = 0.0f, A1 = 0.0f, A2 = 0.0f, A3 = 0.0f;
    int   E  = 0;
    float LC = 0.0f, LP = 0.0f;   // left neighbor's A3 from steps s-1, s-2
    int   EC = 0,    EP = 0;
    float sA3 = 0.0f;             // saved state at s==318 for scalar_out
    int   sEn = 0;

    int s = 0;

    // FIXUP: t==0 handling (fill only). CLAMP: prefetch clamp (tail only).
    // CAP: scalar capture (tail only). Renorm: EVERY step.
#define STEP(MM, II, FIXUP, CLAMP, CAP)                                           \
    {                                                                             \
        const uint2 mw = MM; const half4 in = II;                                 \
        {                                                                         \
            int sp = s + 8;                                                       \
            if (CLAMP) sp = sp > SLABS - 1 ? SLABS - 1 : sp;                      \
            MM = pdu[sp * SS]; II = pi[sp * SS];                                  \
        }                                                                         \
        const float dlx = __builtin_amdgcn_cvt_f32_fp8((int)mw.x, 0);             \
        const float sux = __builtin_amdgcn_cvt_f32_fp8((int)mw.x, 1);             \
        const float dly = __builtin_amdgcn_cvt_f32_fp8((int)mw.x, 2);             \
        const float suy = __builtin_amdgcn_cvt_f32_fp8((int)mw.x, 3);             \
        const float dlz = __builtin_amdgcn_cvt_f32_fp8((int)mw.y, 0);             \
        const float suz = __builtin_amdgcn_cvt_f32_fp8((int)mw.y, 1);             \
        const float dlw = __builtin_amdgcn_cvt_f32_fp8((int)mw.y, 2);             \
        const float suw = __builtin_amdgcn_cvt_f32_fp8((int)mw.y, 3);             \
        int E_eff = E;                                                            \
        bool isT0 = false;                                                        \
        if (FIXUP) {                                                              \
            isT0 = (s == lane);                                                   \
            E_eff = isT0 ? (l0 ? 0 : EC) : E;                                     \
        }                                                                         \
        const float lc = l0 ? 0.0f : ldexpf(LC, EC - E_eff);                      \
        const float lp = l0 ? 0.0f : ldexpf(LP, EP - E_eff);                      \
        float X0 = dlx * A0 + sux * lp;                                           \
        float X1 = dly * A1 + suy * A0;                                           \
        float X2 = dlz * A2 + suz * A1;                                           \
        float X3 = dlw * A3 + suw * A2;                                           \
        if (FIXUP && isT0) {                                                      \
            X0 = l0 ? 1.0f : 0.0f; X1 = 0.0f; X2 = 0.0f; X3 = 0.0f;               \
        }                                                                         \
        const float iy = (float)in.y, iz = (float)in.z, iw = (float)in.w;         \
        const float B0 = X0;                                                      \
        const float B1 = fmaf(B0, iy, X1);                                        \
        const float B2 = fmaf(B1, iz, X2);                                        \
        const float B3 = fmaf(B2, iw, X3);                                        \
        const float Q0 = (float)in.x;                                             \
        const float Q1 = Q0 * iy;                                                 \
        const float Q2 = Q1 * iz;                                                 \
        const float Q3 = Q2 * iw;                                                 \
        float nA0 = fmaf(lc, Q0, B0);                                             \
        float nA1 = fmaf(lc, Q1, B1);                                             \
        float nA2 = fmaf(lc, Q2, B2);                                             \
        float nA3 = fmaf(lc, Q3, B3);                                             \
        /* fused count weights (pre-renorm, common exponent) */                   \
        const float r0 = __builtin_amdgcn_rcpf(nA0);                              \
        const float r1 = __builtin_amdgcn_rcpf(nA1);                              \
        const float r2 = __builtin_amdgcn_rcpf(nA2);                              \
        const float r3 = __builtin_amdgcn_rcpf(nA3);                              \
        half8 hw;                                                                 \
        hw[0] = (_Float16)(dlx * A0 * r0);                                        \
        hw[1] = (_Float16)(dly * A1 * r1);                                        \
        hw[2] = (_Float16)(dlz * A2 * r2);                                        \
        hw[3] = (_Float16)(dlw * A3 * r3);                                        \
        hw[4] = (_Float16)(Q0 * lc * r0);                                         \
        hw[5] = (_Float16)(iy * nA0 * r1);                                        \
        hw[6] = (_Float16)(iz * nA1 * r2);                                        \
        hw[7] = (_Float16)(iw * nA2 * r3);                                        \
        pw[s * 64] = hw;                                                          \
        const int eb = (int)((__float_as_uint(nA3) >> 23) & 255u) - 126;          \
        const int En = E_eff + eb;                                                \
        nA3 = ldexpf(nA3, -eb);                                                   \
        nA0 = ldexpf(nA0, -eb);                                                   \
        nA1 = ldexpf(nA1, -eb);                                                   \
        nA2 = ldexpf(nA2, -eb);                                                   \
        LP = LC; EP = EC;                                                         \
        LC = dpp_shr1_f(nA3);                                                     \
        EC = dpp_shr1_i(En);                                                      \
        if (CAP && s == TT + 62) { sA3 = nA3; sEn = En; }  /* lane63: t==255 */   \
        A0 = nA0; A1 = nA1; A2 = nA2; A3 = nA3; E = En;                           \
        ++s;                                                                      \
    }

    // fill: s=0..63 — full fixups; no clamp needed (s+8<=71)
#pragma unroll 1
    for (int it = 0; it < 8; ++it) {
        STEP(m0, i0, 1, 0, 0);
        STEP(m1, i1, 1, 0, 0);
        STEP(m2, i2, 1, 0, 0);
        STEP(m3, i3, 1, 0, 0);
        STEP(m4, i4, 1, 0, 0);
        STEP(m5, i5, 1, 0, 0);
        STEP(m6, i6, 1, 0, 0);
        STEP(m7, i7, 1, 0, 0);
    }
    // steady: s=64..311 — no fixup, no clamp (s+8<=319)
#pragma unroll 1
    for (int it = 0; it < 31; ++it) {
        STEP(m0, i0, 0, 0, 0);
        STEP(m1, i1, 0, 0, 0);
        STEP(m2, i2, 0, 0, 0);
        STEP(m3, i3, 0, 0, 0);
        STEP(m4, i4, 0, 0, 0);
        STEP(m5, i5, 0, 0, 0);
        STEP(m6, i6, 0, 0, 0);
        STEP(m7, i7, 0, 0, 0);
    }
    // tail: s=312..319 — clamp + scalar capture
    STEP(m0, i0, 0, 1, 1);
    STEP(m1, i1, 0, 1, 1);
    STEP(m2, i2, 0, 1, 1);
    STEP(m3, i3, 0, 1, 1);
    STEP(m4, i4, 0, 1, 1);
    STEP(m5, i5, 0, 1, 1);
    STEP(m6, i6, 0, 1, 1);
    STEP(m7, i7, 0, 1, 1);
#undef STEP

    if ((b == 0) && (lane == 63))
        scalar_out[0] = logf(sA3) + (float)sEn * 0.6931471805599453f;
}

// Kernel 3: pure permute. Cell-per-thread k_prep mapping: block=(b,slab),
// thread j owns v=j, t=s-(j>>2). Reads packed W (per lane-group: 4x w0 then
// 4x w1 fp16), w2=1-w0-w1 (Σw=1, norm==alpha), clamps [0,1] (absorbs rcp
// corner cases), applies the r2-validated edge masks, writes canonical counts.
__global__ void __launch_bounds__(256) k_wperm(const _Float16* __restrict__ W,
                                               float4* __restrict__ out) {
    int blk = blockIdx.x;
    int b = blk / NSLAB_W;
    int s = blk - b * NSLAB_W;
    int v = threadIdx.x;
    int g = v >> 2;
    int k = v & 3;
    int t = s - g;
    if ((t < 0) | (t >= TT)) return;

    size_t wb = (size_t)b * SLABS * 512 + ((size_t)s << 9) + ((size_t)g << 3) + k;
    float w0 = (float)W[wb];
    float w1 = (float)W[wb + 4];
    w0 = fminf(fmaxf(w0, 0.0f), 1.0f);
    w1 = fminf(fmaxf(w1, 0.0f), 1.0f);
    float w2 = fmaxf(0.0f, 1.0f - w0 - w1);

    bool tE = (t == 0) | (t == TT - 1);
    bool vE = (v == 0) | (v == VV - 1);
    float4 o;
    o.x = tE ? 0.0f : (vE ? 1.0f : w0);
    o.y = vE ? 0.0f : (tE ? 1.0f : w1);
    o.z = (tE | vE) ? 0.0f : w2;
    o.w = 0.0f;
    out[((size_t)b << 16) | ((size_t)t << 8) | (size_t)v] = o;
}

// Fallbacks for tiny ws: canonical log_softmax + fused scattered log-domain DP.
__global__ void k_prep_legacy(const float4* __restrict__ lg, float4* __restrict__ sc, int n) {
    int i = blockIdx.x * blockDim.x + threadIdx.x;
    int st = gridDim.x * blockDim.x;
    for (; i < n; i += st) {
        float4 x = lg[i];
        float m = fmaxf(fmaxf(x.x, x.y), fmaxf(x.z, x.w));
        float s = __expf(x.x - m) + __expf(x.y - m) + __expf(x.z - m) + __expf(x.w - m);
        float l = m + __logf(s);
        sc[i] = make_float4(x.x - l, x.y - l, x.z - l, x.w - l);
    }
}
__global__ void __launch_bounds__(64) k_dp_legacy(const float4* __restrict__ scores,
                                                  float4* __restrict__ counts,
                                                  float* __restrict__ scalar_out) {
    const int b = blockIdx.x;
    const int lane = threadIdx.x;
    const int v0 = lane << 2;
    const float4* __restrict__ srow = scores + ((size_t)b * TT * VV + v0);
    float4* __restrict__ crow = counts + ((size_t)b * TT * VV + v0);
    float4 P0[4], P1[4], P2[4];
    {
        int r; const float4* p;
        r = 0 - lane; r = r < 0 ? 0 : r; p = srow + (size_t)r * VV;
        P0[0]=p[0]; P0[1]=p[1]; P0[2]=p[2]; P0[3]=p[3];
        r = 1 - lane; r = r < 0 ? 0 : r; p = srow + (size_t)r * VV;
        P1[0]=p[0]; P1[1]=p[1]; P1[2]=p[2]; P1[3]=p[3];
        r = 2 - lane; r = r < 0 ? 0 : r; p = srow + (size_t)r * VV;
        P2[0]=p[0]; P2[1]=p[1]; P2[2]=p[2]; P2[3]=p[3];
    }
    float aPrev[4] = { -INFINITY, -INFINITY, -INFINITY, -INFINITY };
    float leftPrev = -INFINITY, leftCur = -INFINITY;
    int s = 0;
#define STEPL(BUF)                                                                \
    {                                                                             \
        const int t = s - lane;                                                   \
        const bool active = (t >= 0) && (t < TT);                                 \
        float4 c0 = BUF[0], c1 = BUF[1], c2 = BUF[2], c3 = BUF[3];                \
        {                                                                         \
            int tp = t + 3; tp = tp < 0 ? 0 : tp; tp = tp > TT - 1 ? TT - 1 : tp; \
            const float4* lp = srow + (size_t)tp * VV;                            \
            BUF[0]=lp[0]; BUF[1]=lp[1]; BUF[2]=lp[2]; BUF[3]=lp[3];               \
        }                                                                         \
        float aPm1_0 = (lane == 0) ? -INFINITY : leftPrev;                        \
        float cv0 = lae2(c0.x + aPrev[0], c0.z + aPm1_0);                         \
        float cv1 = lae2(c1.x + aPrev[1], c1.z + aPrev[0]);                       \
        float cv2 = lae2(c2.x + aPrev[2], c2.z + aPrev[1]);                       \
        float cv3 = lae2(c3.x + aPrev[3], c3.z + aPrev[2]);                       \
        if (lane == 0) cv0 = c0.x + aPrev[0];                                     \
        if (t == 0) {                                                             \
            cv0 = (lane == 0) ? 0.0f : -INFINITY;                                 \
            cv1 = -INFINITY; cv2 = -INFINITY; cv3 = -INFINITY;                    \
        }                                                                         \
        float lc = (lane == 0) ? -INFINITY : leftCur;                             \
        float a0 = lae2(lc + c0.y, cv0);                                          \
        float a1 = lae2(a0 + c1.y, cv1);                                          \
        float a2 = lae2(a1 + c2.y, cv2);                                          \
        float a3 = lae2(a2 + c3.y, cv3);                                          \
        if (active) {                                                             \
            const bool tE = (t == 0) | (t == TT - 1);                             \
            float aCm1[4] = { lc, a0, a1, a2 };                                   \
            float aPm1[4] = { aPm1_0, aPrev[0], aPrev[1], aPrev[2] };             \
            float aP[4]   = { aPrev[0], aPrev[1], aPrev[2], aPrev[3] };           \
            float aA[4]   = { a0, a1, a2, a3 };                                   \
            float4 sv[4]  = { c0, c1, c2, c3 };                                   \
            float4* cp = crow + (size_t)t * VV;                                   \
            _Pragma("unroll")                                                     \
            for (int k = 0; k < 4; ++k) {                                         \
                const bool vE = (k == 0 && lane == 0) || (k == 3 && lane == 63);  \
                float w0 = __expf(aP[k]   + sv[k].x - aA[k]);                     \
                float w1 = __expf(aCm1[k] + sv[k].y - aA[k]);                     \
                float w2 = __expf(aPm1[k] + sv[k].z - aA[k]);                     \
                float4 o;                                                         \
                o.x = tE ? 0.0f : (vE ? 1.0f : w0);                               \
                o.y = vE ? 0.0f : (tE ? 1.0f : w1);                               \
                o.z = (tE || vE) ? 0.0f : w2;                                     \
                o.w = 0.0f;                                                       \
                cp[k] = o;                                                        \
            }                                                                     \
            if ((t == TT - 1) && (lane == 63) && (b == 0)) scalar_out[0] = a3;    \
        }                                                                         \
        aPrev[0]=a0; aPrev[1]=a1; aPrev[2]=a2; aPrev[3]=a3;                       \
        leftPrev = leftCur;                                                       \
        leftCur = __shfl_up(a3, 1);                                               \
        ++s;                                                                      \
    }
#pragma unroll 1
    for (int it = 0; it < 107; ++it) { STEPL(P0); STEPL(P1); STEPL(P2); }
#undef STEPL
}

extern "C" void kernel_launch(void* const* d_in, const int* in_sizes, int n_in,
                              void* d_out, int out_size, void* d_ws, size_t ws_size,
                              hipStream_t stream) {
    const float* logits = (const float*)d_in[0];
    float* out = (float*)d_out;
    const size_t ncell = (size_t)BB * TT * VV;

    float4* scores = (float4*)out;                    // output 0: log_softmax
    float4* counts = (float4*)(out + ncell * 4);      // output 1: expected_counts
    float* scalar_out = out + ncell * 8;              // output 2: alpha[0,-1,-1]

    unsigned short* PDU = (unsigned short*)d_ws;   // packed fp8 del|sub [BB][SLABS][256]
    _Float16* Pi = (_Float16*)(PDU + PLANE);       // ins prob plane (fp16)
    _Float16* W  = (_Float16*)(Pi + PLANE);        // packed weights: 512 fp16/slab

    size_t need = PLANE * 2 + PLANE * 2 + PLANE * 4;
    if (ws_size >= need) {
        k_prep<<<BB * NSLAB_W, 256, 0, stream>>>((const float4*)logits, scores, PDU, Pi);
        k_dp<<<BB, 64, 0, stream>>>(PDU, Pi, W, scalar_out);
        k_wperm<<<BB * NSLAB_W, 256, 0, stream>>>(W, counts);
    } else {
        k_prep_legacy<<<2048, 256, 0, stream>>>((const float4*)logits, scores, (int)ncell);
        k_dp_legacy<<<BB, 64, 0, stream>>>(scores, counts, scalar_out);
    }
}